// Round 6
// baseline (271.187 us; speedup 1.0000x reference)
//
#include <hip/hip_runtime.h>
#include <math.h>

#define NPTS   4096   // points per set (n == m)
#define NPROJ  2000   // projections
#define NB     256    // threads per block (4 waves)
#define NMERGE 8192   // n + m
#define VPT    32     // values per thread (in registers)

// XOR-rotate swizzle: element-within-chunk rotated by chunk index (chunk = i>>5).
__device__ __forceinline__ int sw(int i) {
    return (i & ~31) | ((i + (i >> 5)) & 31);
}

// Bitonic local merge of 32 in-register elements, steps j=16..1, uniform direction.
__device__ __forceinline__ void local_merge(float v[VPT], bool asc) {
    #pragma unroll
    for (int j = VPT / 2; j >= 1; j >>= 1) {
        #pragma unroll
        for (int e = 0; e < VPT; ++e) {
            if ((e & j) == 0) {
                float a = v[e], b = v[e | j];
                float mn = fminf(a, b), mx = fmaxf(a, b);
                v[e]     = asc ? mn : mx;
                v[e | j] = asc ? mx : mn;
            }
        }
    }
}

// Empirical launch-bounds rule on this toolchain: VGPR cap = 256 / min_waves.
// (256,4) -> cap 64 (R3: spilled 109 MB); (512,8) -> cap 32 (R4: 268 MB);
// (256,2) -> cap 128: fits the ~100-VGPR need of VPT=32 with NO spill, and
// actual usage <=128 still yields 4 waves/EU at runtime (16 waves/CU, = LDS cap).
__global__ __launch_bounds__(NB, 2) void swd_kernel(
    const float* __restrict__ Xs, const float* __restrict__ Xt,
    const float* __restrict__ Us, float* __restrict__ out)
{
    __shared__ float keys[NMERGE];   // sorted u || sorted v (swizzled); 32 KB
    __shared__ float red[15 * 4];    // per-iteration wave partials

    const int tid  = threadIdx.x;
    const int arr  = tid >> 7;       // 0 = Xs, 1 = Xt
    const int c    = tid & 127;      // chunk index within array (32 elems/chunk)
    const int lane = tid & 63;
    const int wid  = tid >> 6;       // 0..3
    const int p    = blockIdx.x;

    const float u00 = Us[p*6+0], u01 = Us[p*6+1];
    const float u10 = Us[p*6+2], u11 = Us[p*6+3];
    const float u20 = Us[p*6+4], u21 = Us[p*6+5];

    const float pi_f   = 3.14159265358979323846f;
    const float inv2pi = 0.15915494309189535f;

    const float* __restrict__ X = arr ? Xt : Xs;

    // ---- angles into registers (atan2 is scale-invariant; F.normalize skipped) ----
    // sched_barrier after each group keeps only 3 float4 loads live (reg pressure).
    float v[VPT];
    {
        const float4* X4 = (const float4*)(X + c * (VPT * 3));  // 96 floats, 16B aligned
        #pragma unroll
        for (int t = 0; t < 8; ++t) {
            float4 q0 = X4[t*3+0], q1 = X4[t*3+1], q2 = X4[t*3+2];
            #define ANG(x,y,z) ((atan2f(-((x)*u01+(y)*u11+(z)*u21), \
                                        -((x)*u00+(y)*u10+(z)*u20)) + pi_f) * inv2pi)
            v[t*4+0] = ANG(q0.x, q0.y, q0.z);
            v[t*4+1] = ANG(q0.w, q1.x, q1.y);
            v[t*4+2] = ANG(q1.z, q1.w, q2.x);
            v[t*4+3] = ANG(q2.y, q2.z, q2.w);
            #undef ANG
            __builtin_amdgcn_sched_barrier(0);
        }
    }

    // ---- phases k=2..16: intra-thread, compile-time directions ----
    #pragma unroll
    for (int k = 2; k <= 16; k <<= 1) {
        #pragma unroll
        for (int j = k >> 1; j >= 1; j >>= 1) {
            #pragma unroll
            for (int e = 0; e < VPT; ++e) {
                if ((e & j) == 0) {
                    bool asc = ((e & k) == 0);
                    float a = v[e], b = v[e | j];
                    float mn = fminf(a, b), mx = fmaxf(a, b);
                    v[e]     = asc ? mn : mx;
                    v[e | j] = asc ? mx : mn;
                }
            }
        }
    }

    // ---- phase k=32: fully local, direction uniform per thread ----
    local_merge(v, (c & 1) == 0);

    // ---- phases k=64..2048: within-wave shfl_xor exchanges + local merge ----
    #pragma unroll
    for (int k = 64; k <= 2048; k <<= 1) {
        bool asc = ((c & (k >> 5)) == 0);
        #pragma unroll
        for (int d = k >> 6; d >= 1; d >>= 1) {     // j = k/2 .. 32
            bool keepmin = (((c & d) == 0) == asc);
            #pragma unroll
            for (int e = 0; e < VPT; ++e) {
                float o = __shfl_xor(v[e], d, 64);
                v[e] = keepmin ? fminf(v[e], o) : fmaxf(v[e], o);
            }
        }
        local_merge(v, asc);
    }

    // ---- phase k=4096 (full ascending merge) ----
    // j=2048 crosses waves (chunk xor 64): one LDS round-trip.
    #pragma unroll
    for (int e = 0; e < VPT; ++e) keys[sw(tid * VPT + e)] = v[e];
    __syncthreads();
    {
        const int pb = (tid ^ 64) * VPT;
        const bool keepmin = (c & 64) == 0;          // asc = true
        #pragma unroll
        for (int e = 0; e < VPT; ++e) {
            float o = keys[sw(pb + e)];
            v[e] = keepmin ? fminf(v[e], o) : fmaxf(v[e], o);
        }
    }
    __syncthreads();   // all partner reads complete before keys is overwritten
    #pragma unroll
    for (int d = 32; d >= 1; d >>= 1) {              // j = 1024 .. 32
        bool keepmin = ((c & d) == 0);
        #pragma unroll
        for (int e = 0; e < VPT; ++e) {
            float o = __shfl_xor(v[e], d, 64);
            v[e] = keepmin ? fminf(v[e], o) : fmaxf(v[e], o);
        }
    }
    local_merge(v, true);

    // store sorted arrays for the merge
    #pragma unroll
    for (int e = 0; e < VPT; ++e) keys[sw(tid * VPT + e)] = v[e];
    __syncthreads();

    // ---- merge-path merge; keep (delta, c-offset) per element in registers ----
    // Level after merged element = (#u taken) - (#v taken); cdf value = c/4096 exact.
    int c_init;
    unsigned int c8[8] = {0,0,0,0,0,0,0,0};
    {
        const int d0 = tid * VPT;
        int lo = d0 > NPTS ? d0 - NPTS : 0;
        int hi = d0 < NPTS ? d0 : NPTS;
        while (lo < hi) {                     // ties: u first (stable argsort)
            int mid = (lo + hi) >> 1;
            if (keys[sw(mid)] <= keys[sw(NPTS + (d0 - 1 - mid))]) lo = mid + 1; else hi = mid;
        }
        int i = lo, j = d0 - lo;
        c_init = i - j;
        const float FMAXV = 3.402823466e+38f;
        float cu = (i < NPTS) ? keys[sw(i)] : FMAXV;
        float cv = (j < NPTS) ? keys[sw(NPTS + j)] : FMAXV;
        #pragma unroll
        for (int s = 0; s < VPT; ++s) {
            float cur;
            if (cu <= cv) { cur = cu; ++i; cu = (i < NPTS) ? keys[sw(i)] : FMAXV; }
            else          { cur = cv; ++j; cv = (j < NPTS) ? keys[sw(NPTS + j)] : FMAXV; }
            float nxt = fminf(cu, cv);
            if (nxt == FMAXV) nxt = 1.0f;     // vals_pad appends 1.0
            v[s] = nxt - cur;                 // delta (>= 0)
            int off = (i - j) - c_init;       // in [-32, 32]
            c8[s >> 2] |= ((unsigned int)(off & 0xff)) << ((s & 3) * 8);
        }
    }

    // ---- level median c* via integer bisection (no histogram, no atomics) ----
    int lo_c = -4097, hi_c = 4096;
    #pragma unroll 1
    for (int it = 0; it < 14; ++it) {
        const int mid = (lo_c + hi_c) >> 1;   // uniform across block
        const int thr = mid - c_init;
        float s_loc = 0.0f;
        #pragma unroll
        for (int s = 0; s < VPT; ++s) {
            int off = (int)(c8[s >> 2] << ((3 - (s & 3)) * 8)) >> 24;  // sign-extended byte
            s_loc += (off <= thr) ? v[s] : 0.0f;
        }
        #pragma unroll
        for (int o = 32; o >= 1; o >>= 1) s_loc += __shfl_down(s_loc, o, 64);
        if (lane == 0) red[it * 4 + wid] = s_loc;
        __syncthreads();
        float S = red[it*4+0] + red[it*4+1] + red[it*4+2] + red[it*4+3];
        if (S >= 0.5f) hi_c = mid; else lo_c = mid;
    }
    const int cstar = hi_c;

    // ---- w1 = (1/4096) * sum delta * |c - c*| ----
    float part = 0.0f;
    {
        const int thr = cstar - c_init;
        #pragma unroll
        for (int s = 0; s < VPT; ++s) {
            int off = (int)(c8[s >> 2] << ((3 - (s & 3)) * 8)) >> 24;
            part += v[s] * fabsf((float)(off - thr));
        }
    }
    #pragma unroll
    for (int o = 32; o >= 1; o >>= 1) part += __shfl_down(part, o, 64);
    if (lane == 0) red[56 + wid] = part;
    __syncthreads();
    if (tid == 0) {
        float w1 = (red[56] + red[57] + red[58] + red[59]) * (1.0f / 4096.0f);
        atomicAdd(out, w1 * (1.0f / (float)NPROJ));
    }
}

extern "C" void kernel_launch(void* const* d_in, const int* in_sizes, int n_in,
                              void* d_out, int out_size, void* d_ws, size_t ws_size,
                              hipStream_t stream) {
    const float* Xs = (const float*)d_in[0];
    const float* Xt = (const float*)d_in[1];
    const float* Us = (const float*)d_in[2];
    float* out = (float*)d_out;

    hipMemsetAsync(out, 0, sizeof(float), stream);
    swd_kernel<<<NPROJ, NB, 0, stream>>>(Xs, Xt, Us, out);
}

// Round 7
// 258.038 us; speedup vs baseline: 1.0510x; 1.0510x over previous
//
#include <hip/hip_runtime.h>
#include <math.h>

#define NPTS   4096   // points per set (n == m)
#define NPROJ  2000   // projections
#define NB     256    // threads per block (4 waves)
#define NMERGE 8192   // n + m
#define VPT    32     // values per thread (in registers)

// XOR-rotate swizzle: element-within-chunk rotated by chunk index (chunk = i>>5).
__device__ __forceinline__ int sw(int i) {
    return (i & ~31) | ((i + (i >> 5)) & 31);
}

// Bitonic local merge of 32 in-register elements, steps j=16..1, uniform direction.
__device__ __forceinline__ void local_merge(float v[VPT], bool asc) {
    #pragma unroll
    for (int j = VPT / 2; j >= 1; j >>= 1) {
        #pragma unroll
        for (int e = 0; e < VPT; ++e) {
            if ((e & j) == 0) {
                float a = v[e], b = v[e | j];
                float mn = fminf(a, b), mx = fmaxf(a, b);
                v[e]     = asc ? mn : mx;
                v[e | j] = asc ? mx : mn;
            }
        }
    }
}

// __launch_bounds__(256) ONLY — no min-waves arg. Empirically on this toolchain
// the 2nd arg acts as BOTH a VGPR budget (cap ~ 256/min_waves: R3=64 spill,
// R4=32 heavy spill, R5=48, R6=96) AND an occupancy cap (~min_waves/EU:
// R2/R6 ~25%, R3/R5 ~50%, R4 ~75-100%). Undeclared: allocator is need-based
// (~96-128, no spill) and occupancy rises to the LDS cap (33 KB -> 4 blocks/CU
// = 16 waves = 50%), with VGPR<=128 -> >=4 waves/SIMD, not binding.
__global__ __launch_bounds__(NB) void swd_kernel(
    const float* __restrict__ Xs, const float* __restrict__ Xt,
    const float* __restrict__ Us, float* __restrict__ out)
{
    __shared__ float keys[NMERGE];   // sorted u || sorted v (swizzled); 32 KB
    __shared__ float red[15 * 4];    // per-iteration wave partials

    const int tid  = threadIdx.x;
    const int arr  = tid >> 7;       // 0 = Xs, 1 = Xt
    const int c    = tid & 127;      // chunk index within array (32 elems/chunk)
    const int lane = tid & 63;
    const int wid  = tid >> 6;       // 0..3
    const int p    = blockIdx.x;

    const float u00 = Us[p*6+0], u01 = Us[p*6+1];
    const float u10 = Us[p*6+2], u11 = Us[p*6+3];
    const float u20 = Us[p*6+4], u21 = Us[p*6+5];

    const float pi_f   = 3.14159265358979323846f;
    const float inv2pi = 0.15915494309189535f;

    const float* __restrict__ X = arr ? Xt : Xs;

    // ---- angles into registers (atan2 is scale-invariant; F.normalize skipped) ----
    // sched_barrier after each group keeps only 3 float4 loads live (reg pressure).
    float v[VPT];
    {
        const float4* X4 = (const float4*)(X + c * (VPT * 3));  // 96 floats, 16B aligned
        #pragma unroll
        for (int t = 0; t < 8; ++t) {
            float4 q0 = X4[t*3+0], q1 = X4[t*3+1], q2 = X4[t*3+2];
            #define ANG(x,y,z) ((atan2f(-((x)*u01+(y)*u11+(z)*u21), \
                                        -((x)*u00+(y)*u10+(z)*u20)) + pi_f) * inv2pi)
            v[t*4+0] = ANG(q0.x, q0.y, q0.z);
            v[t*4+1] = ANG(q0.w, q1.x, q1.y);
            v[t*4+2] = ANG(q1.z, q1.w, q2.x);
            v[t*4+3] = ANG(q2.y, q2.z, q2.w);
            #undef ANG
            __builtin_amdgcn_sched_barrier(0);
        }
    }

    // ---- phases k=2..16: intra-thread, compile-time directions ----
    #pragma unroll
    for (int k = 2; k <= 16; k <<= 1) {
        #pragma unroll
        for (int j = k >> 1; j >= 1; j >>= 1) {
            #pragma unroll
            for (int e = 0; e < VPT; ++e) {
                if ((e & j) == 0) {
                    bool asc = ((e & k) == 0);
                    float a = v[e], b = v[e | j];
                    float mn = fminf(a, b), mx = fmaxf(a, b);
                    v[e]     = asc ? mn : mx;
                    v[e | j] = asc ? mx : mn;
                }
            }
        }
    }

    // ---- phase k=32: fully local, direction uniform per thread ----
    local_merge(v, (c & 1) == 0);

    // ---- phases k=64..2048: within-wave shfl_xor exchanges + local merge ----
    #pragma unroll
    for (int k = 64; k <= 2048; k <<= 1) {
        bool asc = ((c & (k >> 5)) == 0);
        #pragma unroll
        for (int d = k >> 6; d >= 1; d >>= 1) {     // j = k/2 .. 32
            bool keepmin = (((c & d) == 0) == asc);
            #pragma unroll
            for (int e = 0; e < VPT; ++e) {
                float o = __shfl_xor(v[e], d, 64);
                v[e] = keepmin ? fminf(v[e], o) : fmaxf(v[e], o);
            }
        }
        local_merge(v, asc);
    }

    // ---- phase k=4096 (full ascending merge) ----
    // j=2048 crosses waves (chunk xor 64): one LDS round-trip.
    #pragma unroll
    for (int e = 0; e < VPT; ++e) keys[sw(tid * VPT + e)] = v[e];
    __syncthreads();
    {
        const int pb = (tid ^ 64) * VPT;
        const bool keepmin = (c & 64) == 0;          // asc = true
        #pragma unroll
        for (int e = 0; e < VPT; ++e) {
            float o = keys[sw(pb + e)];
            v[e] = keepmin ? fminf(v[e], o) : fmaxf(v[e], o);
        }
    }
    __syncthreads();   // all partner reads complete before keys is overwritten
    #pragma unroll
    for (int d = 32; d >= 1; d >>= 1) {              // j = 1024 .. 32
        bool keepmin = ((c & d) == 0);
        #pragma unroll
        for (int e = 0; e < VPT; ++e) {
            float o = __shfl_xor(v[e], d, 64);
            v[e] = keepmin ? fminf(v[e], o) : fmaxf(v[e], o);
        }
    }
    local_merge(v, true);

    // store sorted arrays for the merge
    #pragma unroll
    for (int e = 0; e < VPT; ++e) keys[sw(tid * VPT + e)] = v[e];
    __syncthreads();

    // ---- merge-path merge; keep (delta, c-offset) per element in registers ----
    // Level after merged element = (#u taken) - (#v taken); cdf value = c/4096 exact.
    int c_init;
    unsigned int c8[8] = {0,0,0,0,0,0,0,0};
    {
        const int d0 = tid * VPT;
        int lo = d0 > NPTS ? d0 - NPTS : 0;
        int hi = d0 < NPTS ? d0 : NPTS;
        while (lo < hi) {                     // ties: u first (stable argsort)
            int mid = (lo + hi) >> 1;
            if (keys[sw(mid)] <= keys[sw(NPTS + (d0 - 1 - mid))]) lo = mid + 1; else hi = mid;
        }
        int i = lo, j = d0 - lo;
        c_init = i - j;
        const float FMAXV = 3.402823466e+38f;
        float cu = (i < NPTS) ? keys[sw(i)] : FMAXV;
        float cv = (j < NPTS) ? keys[sw(NPTS + j)] : FMAXV;
        #pragma unroll
        for (int s = 0; s < VPT; ++s) {
            float cur;
            if (cu <= cv) { cur = cu; ++i; cu = (i < NPTS) ? keys[sw(i)] : FMAXV; }
            else          { cur = cv; ++j; cv = (j < NPTS) ? keys[sw(NPTS + j)] : FMAXV; }
            float nxt = fminf(cu, cv);
            if (nxt == FMAXV) nxt = 1.0f;     // vals_pad appends 1.0
            v[s] = nxt - cur;                 // delta (>= 0)
            int off = (i - j) - c_init;       // in [-32, 32]
            c8[s >> 2] |= ((unsigned int)(off & 0xff)) << ((s & 3) * 8);
        }
    }

    // ---- level median c* via integer bisection (no histogram, no atomics) ----
    int lo_c = -4097, hi_c = 4096;
    #pragma unroll 1
    for (int it = 0; it < 14; ++it) {
        const int mid = (lo_c + hi_c) >> 1;   // uniform across block
        const int thr = mid - c_init;
        float s_loc = 0.0f;
        #pragma unroll
        for (int s = 0; s < VPT; ++s) {
            int off = (int)(c8[s >> 2] << ((3 - (s & 3)) * 8)) >> 24;  // sign-extended byte
            s_loc += (off <= thr) ? v[s] : 0.0f;
        }
        #pragma unroll
        for (int o = 32; o >= 1; o >>= 1) s_loc += __shfl_down(s_loc, o, 64);
        if (lane == 0) red[it * 4 + wid] = s_loc;
        __syncthreads();
        float S = red[it*4+0] + red[it*4+1] + red[it*4+2] + red[it*4+3];
        if (S >= 0.5f) hi_c = mid; else lo_c = mid;
    }
    const int cstar = hi_c;

    // ---- w1 = (1/4096) * sum delta * |c - c*| ----
    float part = 0.0f;
    {
        const int thr = cstar - c_init;
        #pragma unroll
        for (int s = 0; s < VPT; ++s) {
            int off = (int)(c8[s >> 2] << ((3 - (s & 3)) * 8)) >> 24;
            part += v[s] * fabsf((float)(off - thr));
        }
    }
    #pragma unroll
    for (int o = 32; o >= 1; o >>= 1) part += __shfl_down(part, o, 64);
    if (lane == 0) red[56 + wid] = part;
    __syncthreads();
    if (tid == 0) {
        float w1 = (red[56] + red[57] + red[58] + red[59]) * (1.0f / 4096.0f);
        atomicAdd(out, w1 * (1.0f / (float)NPROJ));
    }
}

extern "C" void kernel_launch(void* const* d_in, const int* in_sizes, int n_in,
                              void* d_out, int out_size, void* d_ws, size_t ws_size,
                              hipStream_t stream) {
    const float* Xs = (const float*)d_in[0];
    const float* Xt = (const float*)d_in[1];
    const float* Us = (const float*)d_in[2];
    float* out = (float*)d_out;

    hipMemsetAsync(out, 0, sizeof(float), stream);
    swd_kernel<<<NPROJ, NB, 0, stream>>>(Xs, Xt, Us, out);
}